// Round 6
// baseline (100.261 us; speedup 1.0000x reference)
//
#include <hip/hip_runtime.h>
#include <cstdint>
#include <cstddef>

#define NN 8192
#define INF 512
#define OUTF 64
#define ALPHA 0.2f
#define NSPLIT 16
#define JSPLIT (NN / NSPLIT)   // 512
#define NW32 (NN / 32)         // 256 mask words per row
#define GEMM_BLOCKS 512

typedef short bf16x8 __attribute__((ext_vector_type(8)));
typedef float f32x4 __attribute__((ext_vector_type(4)));

static __device__ inline unsigned short f2bf(float f) {
    unsigned u = __builtin_bit_cast(unsigned, f);
    unsigned r = (u + 0x7FFFu + ((u >> 16) & 1u)) >> 16;
    return (unsigned short)r;
}

// ---------------------------------------------------------------------------
// Kernel 01 (fused): blocks 0..511 = GEMM (LDS-free, scalar-x), blocks
// 512..8703 = adj->bitmask pack. GEMM epilogue also precomputes the factored
// exp vectors: Tp=exp(-s1), E1p=exp(s1), E1n=exp(.2 s1), E2p=exp(s2),
// E2n=exp(.2 s2)  — so k2's inner loop has NO transcendentals.
// ---------------------------------------------------------------------------
__global__ __launch_bounds__(256) void k01_fused(
    const float* __restrict__ x, const int* __restrict__ adj,
    const float* __restrict__ W, const float* __restrict__ a,
    unsigned short* __restrict__ Asw, float* __restrict__ Tp,
    float* __restrict__ E1p, float* __restrict__ E1n,
    float* __restrict__ E2p, float* __restrict__ E2n,
    unsigned* __restrict__ mask)
{
    __shared__ int ldsbuf[8192];   // 32 KB (mask path only)
    const int tid = threadIdx.x;

    if (blockIdx.x >= GEMM_BLOCKS) {
        // ---------------- mask path: one adj row ----------------
        const int row = blockIdx.x - GEMM_BLOCKS;
        const int* arow = adj + (size_t)row * NN;

        #pragma unroll
        for (int k = 0; k < 8; ++k) {
            const int i = k * 1024 + tid * 4;
            int4 v = *(const int4*)(arow + i);
            const int p = i ^ (((i >> 7) & 7) << 2);
            *(int4*)&ldsbuf[p] = v;
        }
        __syncthreads();

        unsigned m = 0;
        #pragma unroll
        for (int k = 0; k < 8; ++k) {
            const int i2 = tid * 32 + k * 4;
            const int p2 = i2 ^ (((i2 >> 7) & 7) << 2);
            int4 v = *(const int4*)&ldsbuf[p2];
            m |= (v.x != 0 ? 1u : 0u) << (4 * k);
            m |= (v.y != 0 ? 1u : 0u) << (4 * k + 1);
            m |= (v.z != 0 ? 1u : 0u) << (4 * k + 2);
            m |= (v.w != 0 ? 1u : 0u) << (4 * k + 3);
        }
        mask[(size_t)row * NW32 + tid] = m;
        return;
    }

    // ---------------- GEMM path: 16 rows of Wh per block ----------------
    const int i0 = blockIdx.x * 16;
    const int w  = __builtin_amdgcn_readfirstlane(tid >> 6);
    const int c  = tid & 63;

    const float* xr = x + (size_t)(i0 + 4 * w) * INF;
    const float* Wc = W + c;
    float acc[4] = {0.f, 0.f, 0.f, 0.f};

    #pragma unroll 4
    for (int kk = 0; kk < 128; ++kk) {
        const float4 x0 = *(const float4*)(xr + 0 * INF + kk * 4);
        const float4 x1 = *(const float4*)(xr + 1 * INF + kk * 4);
        const float4 x2 = *(const float4*)(xr + 2 * INF + kk * 4);
        const float4 x3 = *(const float4*)(xr + 3 * INF + kk * 4);
        const float w0 = Wc[(kk * 4 + 0) * OUTF];
        const float w1 = Wc[(kk * 4 + 1) * OUTF];
        const float w2 = Wc[(kk * 4 + 2) * OUTF];
        const float w3 = Wc[(kk * 4 + 3) * OUTF];
        acc[0] = fmaf(x0.x, w0, fmaf(x0.y, w1, fmaf(x0.z, w2, fmaf(x0.w, w3, acc[0]))));
        acc[1] = fmaf(x1.x, w0, fmaf(x1.y, w1, fmaf(x1.z, w2, fmaf(x1.w, w3, acc[1]))));
        acc[2] = fmaf(x2.x, w0, fmaf(x2.y, w1, fmaf(x2.z, w2, fmaf(x2.w, w3, acc[2]))));
        acc[3] = fmaf(x3.x, w0, fmaf(x3.y, w1, fmaf(x3.z, w2, fmaf(x3.w, w3, acc[3]))));
    }

    const float a1c = a[c];
    const float a2c = a[64 + c];
    #pragma unroll
    for (int q = 0; q < 4; ++q) {
        float v1 = acc[q] * a1c;
        float v2 = acc[q] * a2c;
        #pragma unroll
        for (int m = 32; m; m >>= 1) {
            v1 += __shfl_xor(v1, m, 64);
            v2 += __shfl_xor(v2, m, 64);
        }
        if (c == 0) {
            const int i = i0 + 4 * w + q;
            Tp[i]  = __expf(-v1);
            E1p[i] = __expf(v1);
            E1n[i] = __expf(ALPHA * v1);
            E2p[i] = __expf(v2);
            E2n[i] = __expf(ALPHA * v2);
        }
    }

    // A-fragment-swizzled store (verified layout, unchanged)
    const int i   = i0 + 4 * w;
    const int jt  = i >> 5;
    const int sub = (i >> 3) & 3;
    const int e0  = i & 7;
    ushort4 pk;
    pk.x = f2bf(acc[0]); pk.y = f2bf(acc[1]);
    pk.z = f2bf(acc[2]); pk.w = f2bf(acc[3]);
    *(ushort4*)&Asw[((size_t)(c >> 4) * 256 + jt) * 512 + ((c & 15) + 16 * sub) * 8 + e0] = pk;
}

// ---------------------------------------------------------------------------
// Kernel 2: fused masked-softmax attention. Barrier-free, LDS-free, and now
// transcendental-free: p = mask * (s1+s2>0 ? E1p[i]*E2p[j] : E1n[i]*E2n[j]),
// sign test done in exp domain (E2p[j] > Tp[i]). Row sums computed on the
// matrix pipe via an all-ones A-fragment MFMA (full K-reduction, no shuffles).
// ---------------------------------------------------------------------------
__global__ __launch_bounds__(256) void k2_attn(
    const unsigned* __restrict__ mask, const unsigned short* __restrict__ Asw,
    const float* __restrict__ Tpg, const float* __restrict__ E1pg,
    const float* __restrict__ E1ng, const float* __restrict__ E2pg,
    const float* __restrict__ E2ng,
    float* __restrict__ Opart, float* __restrict__ lpart)
{
    const int tid   = threadIdx.x;
    const int l     = tid & 63;
    const int w     = tid >> 6;
    const int task  = blockIdx.x * 4 + w;      // 0..4095
    const int it    = task >> 4;               // 0..255
    const int split = task & 15;
    const int i0    = it * 32;
    const int jbase = split * JSPLIT;
    const int jb32  = jbase >> 5;

    const int il  = l & 15;
    const int kg  = l >> 4;
    const int kg8 = kg * 8;

    const float tpa  = Tpg[i0 + il],      tpb  = Tpg[i0 + 16 + il];
    const float e1pa = E1pg[i0 + il],     e1pb = E1pg[i0 + 16 + il];
    const float e1na = E1ng[i0 + il],     e1nb = E1ng[i0 + 16 + il];

    const unsigned* mbase = mask + (size_t)(i0 + il) * NW32 + jb32 + kg;

    bf16x8 ONES;
    #pragma unroll
    for (int e = 0; e < 8; ++e) ONES[e] = (short)0x3F80;   // bf16 1.0

    f32x4 a00 = {0,0,0,0}, a01 = {0,0,0,0}, a10 = {0,0,0,0}, a11 = {0,0,0,0};
    f32x4 a20 = {0,0,0,0}, a21 = {0,0,0,0}, a30 = {0,0,0,0}, a31 = {0,0,0,0};
    f32x4 sA  = {0,0,0,0}, sB  = {0,0,0,0};

    const unsigned short* A8 = Asw + (size_t)jb32 * 512 + l * 8;
    bf16x8 A0c = *(const bf16x8*)(A8);
    bf16x8 A1c = *(const bf16x8*)(A8 + 131072);
    bf16x8 A2c = *(const bf16x8*)(A8 + 262144);
    bf16x8 A3c = *(const bf16x8*)(A8 + 393216);

    unsigned mwA = 0, mwB = 0;

// score: cmp in exp domain + 2 cndmask + mul + mask-select; no transcendentals
#define SCORE(E2PV, E2NV, BITS, K, TPV, E1PV, E1NV)                            \
    ({  const bool pos_ = (E2PV) > (TPV);                                      \
        const float e1_ = pos_ ? (E1PV) : (E1NV);                              \
        const float e2_ = pos_ ? (E2PV) : (E2NV);                              \
        (((BITS) >> (K)) & 1u) ? e1_ * e2_ : 0.f;  })

    #pragma unroll
    for (int t = 0; t < 16; ++t) {
        const int ss = t >> 2, ks = t & 3;
        if (ks == 0) {                       // static under full unroll
            mwA = mbase[ss * 4];
            mwB = mbase[(size_t)16 * NW32 + ss * 4];
        }

        // prefetch next step's A-fragments (last step reloads itself)
        const int tn = (t < 15) ? t + 1 : t;
        const unsigned short* An = Asw + (size_t)(jb32 + tn) * 512 + l * 8;
        bf16x8 A0n = *(const bf16x8*)(An);
        bf16x8 A1n = *(const bf16x8*)(An + 131072);
        bf16x8 A2n = *(const bf16x8*)(An + 262144);
        bf16x8 A3n = *(const bf16x8*)(An + 393216);

        const unsigned bA = (__shfl(mwA, il + 16 * ks, 64) >> kg8) & 0xffu;
        const unsigned bB = (__shfl(mwB, il + 16 * ks, 64) >> kg8) & 0xffu;

        const int jo = jbase + t * 32 + kg8;
        const float4 ppa = *(const float4*)(E2pg + jo);
        const float4 ppb = *(const float4*)(E2pg + jo + 4);
        const float4 pna = *(const float4*)(E2ng + jo);
        const float4 pnb = *(const float4*)(E2ng + jo + 4);

        const float p0 = SCORE(ppa.x, pna.x, bA, 0, tpa, e1pa, e1na);
        const float p1 = SCORE(ppa.y, pna.y, bA, 1, tpa, e1pa, e1na);
        const float p2 = SCORE(ppa.z, pna.z, bA, 2, tpa, e1pa, e1na);
        const float p3 = SCORE(ppa.w, pna.w, bA, 3, tpa, e1pa, e1na);
        const float p4 = SCORE(ppb.x, pnb.x, bA, 4, tpa, e1pa, e1na);
        const float p5 = SCORE(ppb.y, pnb.y, bA, 5, tpa, e1pa, e1na);
        const float p6 = SCORE(ppb.z, pnb.z, bA, 6, tpa, e1pa, e1na);
        const float p7 = SCORE(ppb.w, pnb.w, bA, 7, tpa, e1pa, e1na);
        const float q0 = SCORE(ppa.x, pna.x, bB, 0, tpb, e1pb, e1nb);
        const float q1 = SCORE(ppa.y, pna.y, bB, 1, tpb, e1pb, e1nb);
        const float q2 = SCORE(ppa.z, pna.z, bB, 2, tpb, e1pb, e1nb);
        const float q3 = SCORE(ppa.w, pna.w, bB, 3, tpb, e1pb, e1nb);
        const float q4 = SCORE(ppb.x, pnb.x, bB, 4, tpb, e1pb, e1nb);
        const float q5 = SCORE(ppb.y, pnb.y, bB, 5, tpb, e1pb, e1nb);
        const float q6 = SCORE(ppb.z, pnb.z, bB, 6, tpb, e1pb, e1nb);
        const float q7 = SCORE(ppb.w, pnb.w, bB, 7, tpb, e1pb, e1nb);

        uint4 wa, wb;
        asm("v_cvt_pk_bf16_f32 %0, %1, %2" : "=v"(wa.x) : "v"(p0), "v"(p1));
        asm("v_cvt_pk_bf16_f32 %0, %1, %2" : "=v"(wa.y) : "v"(p2), "v"(p3));
        asm("v_cvt_pk_bf16_f32 %0, %1, %2" : "=v"(wa.z) : "v"(p4), "v"(p5));
        asm("v_cvt_pk_bf16_f32 %0, %1, %2" : "=v"(wa.w) : "v"(p6), "v"(p7));
        asm("v_cvt_pk_bf16_f32 %0, %1, %2" : "=v"(wb.x) : "v"(q0), "v"(q1));
        asm("v_cvt_pk_bf16_f32 %0, %1, %2" : "=v"(wb.y) : "v"(q2), "v"(q3));
        asm("v_cvt_pk_bf16_f32 %0, %1, %2" : "=v"(wb.z) : "v"(q4), "v"(q5));
        asm("v_cvt_pk_bf16_f32 %0, %1, %2" : "=v"(wb.w) : "v"(q6), "v"(q7));
        const bf16x8 BA = __builtin_bit_cast(bf16x8, wa);
        const bf16x8 BB = __builtin_bit_cast(bf16x8, wb);

        // row-sums on the matrix pipe (full K-reduction incl. cross-lane)
        sA  = __builtin_amdgcn_mfma_f32_16x16x32_bf16(ONES, BA, sA, 0, 0, 0);
        sB  = __builtin_amdgcn_mfma_f32_16x16x32_bf16(ONES, BB, sB, 0, 0, 0);

        a00 = __builtin_amdgcn_mfma_f32_16x16x32_bf16(A0c, BA, a00, 0, 0, 0);
        a01 = __builtin_amdgcn_mfma_f32_16x16x32_bf16(A0c, BB, a01, 0, 0, 0);
        a10 = __builtin_amdgcn_mfma_f32_16x16x32_bf16(A1c, BA, a10, 0, 0, 0);
        a11 = __builtin_amdgcn_mfma_f32_16x16x32_bf16(A1c, BB, a11, 0, 0, 0);
        a20 = __builtin_amdgcn_mfma_f32_16x16x32_bf16(A2c, BA, a20, 0, 0, 0);
        a21 = __builtin_amdgcn_mfma_f32_16x16x32_bf16(A2c, BB, a21, 0, 0, 0);
        a30 = __builtin_amdgcn_mfma_f32_16x16x32_bf16(A3c, BA, a30, 0, 0, 0);
        a31 = __builtin_amdgcn_mfma_f32_16x16x32_bf16(A3c, BB, a31, 0, 0, 0);

        A0c = A0n; A1c = A1n; A2c = A2n; A3c = A3n;
    }
#undef SCORE

    // lpart: lane l<16 (kg=0) holds D[0][il] = full split row-sum
    if (l < 16) {
        lpart[(size_t)split * NN + i0 + il]      = sA[0];
        lpart[(size_t)split * NN + i0 + 16 + il] = sB[0];
    }

    const int nn = kg * 4;
    float* OA = Opart + ((size_t)split * NN + i0 + il) * OUTF + nn;
    float* OB = OA + (size_t)16 * OUTF;
    *(float4*)(OA)      = *(float4*)&a00;
    *(float4*)(OA + 16) = *(float4*)&a10;
    *(float4*)(OA + 32) = *(float4*)&a20;
    *(float4*)(OA + 48) = *(float4*)&a30;
    *(float4*)(OB)      = *(float4*)&a01;
    *(float4*)(OB + 16) = *(float4*)&a11;
    *(float4*)(OB + 32) = *(float4*)&a21;
    *(float4*)(OB + 48) = *(float4*)&a31;
}

// ---------------------------------------------------------------------------
// Kernel 3: combine the 16 j-split partials and normalize.
// ---------------------------------------------------------------------------
__global__ __launch_bounds__(256) void k3_combine(
    const float* __restrict__ Opart, const float* __restrict__ lpart,
    float* __restrict__ out)
{
    const int f4 = blockIdx.x * 256 + threadIdx.x;   // 0..131071
    const int i  = f4 >> 4;

    float4 r = {0.f, 0.f, 0.f, 0.f};
    float  lsum = 0.f;
    #pragma unroll
    for (int s = 0; s < NSPLIT; ++s) {
        float4 o = *(const float4*)&Opart[(size_t)s * NN * OUTF + (size_t)f4 * 4];
        r.x += o.x; r.y += o.y; r.z += o.z; r.w += o.w;
        lsum += lpart[(size_t)s * NN + i];
    }
    float inv = 1.0f / lsum;
    r.x *= inv; r.y *= inv; r.z *= inv; r.w *= inv;
    *(float4*)&out[(size_t)f4 * 4] = r;
}

extern "C" void kernel_launch(void* const* d_in, const int* in_sizes, int n_in,
                              void* d_out, int out_size, void* d_ws, size_t ws_size,
                              hipStream_t stream) {
    const float* x   = (const float*)d_in[0];
    const int*   adj = (const int*)d_in[1];
    const float* W   = (const float*)d_in[2];
    const float* a   = (const float*)d_in[3];
    float* out = (float*)d_out;

    char* ws = (char*)d_ws;
    unsigned short* Asw = (unsigned short*)ws;                        // 1 MB
    float* Tp    = (float*)(ws + (1 << 20));                          // 32 KB
    float* E1p   = (float*)(ws + (1 << 20) + 32768);                  // 32 KB
    float* E1n   = (float*)(ws + (1 << 20) + 65536);                  // 32 KB
    float* E2p   = (float*)(ws + (1 << 20) + 98304);                  // 32 KB
    float* E2n   = (float*)(ws + (1 << 20) + 131072);                 // 32 KB
    float* lpart = (float*)(ws + (1 << 20) + 163840);                 // 512 KB
    unsigned* mask = (unsigned*)(ws + (1 << 20) + 163840 + 524288);   // 8 MB
    float* Opart = (float*)(ws + (1 << 20) + 163840 + 524288 + (8 << 20)); // 32 MB

    k01_fused<<<GEMM_BLOCKS + NN, 256, 0, stream>>>(x, adj, W, a, Asw,
                                                    Tp, E1p, E1n, E2p, E2n, mask);
    k2_attn<<<1024, 256, 0, stream>>>(mask, Asw, Tp, E1p, E1n, E2p, E2n,
                                      Opart, lpart);
    k3_combine<<<512, 256, 0, stream>>>(Opart, lpart, out);
}